// Round 2
// baseline (250.962 us; speedup 1.0000x reference)
//
#include <hip/hip_runtime.h>
#include <math.h>

#define NN 4096
#define DD 256
#define NH 8
#define EE 131072
#define MAXD 256
#define QR 8            // nodes per block in GEMM kernels

// ---------------- K1: scatter edges into a 4096x4096 bitset (symmetric, no self) ----------------
__global__ void k_edges(const int* __restrict__ ei, unsigned* __restrict__ adj){
    int e = blockIdx.x * 256 + threadIdx.x;
    int s = ei[e];
    int d = ei[EE + e];
    if (s != d){
        atomicOr(&adj[s * 128 + (d >> 5)], 1u << (d & 31));
        atomicOr(&adj[d * 128 + (s >> 5)], 1u << (s & 31));
    }
}

// ---------------- K2: bitset row -> compact neighbor list + degree (1 wave / node) ----------------
__global__ void k_nbr(const unsigned* __restrict__ adj, int* __restrict__ nbr, int* __restrict__ deg){
    int n = blockIdx.x;
    int lane = threadIdx.x;
    unsigned w0 = adj[n * 128 + 2 * lane];
    unsigned w1 = adj[n * 128 + 2 * lane + 1];
    int cnt = __popc(w0) + __popc(w1);
    int pre = cnt;
    #pragma unroll
    for (int off = 1; off < 64; off <<= 1){
        int t = __shfl_up(pre, off);
        if (lane >= off) pre += t;
    }
    int base = pre - cnt;            // exclusive prefix
    int mb = lane * 64;
    while (w0){ int b = __ffs(w0) - 1; w0 &= w0 - 1u; if (base < MAXD) nbr[n * MAXD + base] = mb + b; base++; }
    mb += 32;
    while (w1){ int b = __ffs(w1) - 1; w1 &= w1 - 1u; if (base < MAXD) nbr[n * MAXD + base] = mb + b; base++; }
    if (lane == 63) deg[n] = (pre < MAXD) ? pre : MAXD;   // inclusive total at lane 63
}

// ---------------- K3: QKV projection, 8 nodes/block: qkv[n,o] = emb[n,:] . W[o,:] + b[o] ----------
__global__ void k_qkv(const float* __restrict__ emb, const float* __restrict__ w,
                      const float* __restrict__ b, float* __restrict__ qkv){
    __shared__ float se[QR][DD];
    int t = threadIdx.x;
    int n0 = blockIdx.y * QR;
    for (int i = t; i < QR * DD; i += 256)
        se[i >> 8][i & 255] = emb[n0 * DD + i];
    __syncthreads();
    int o = blockIdx.x * 256 + t;
    const float4* wr = (const float4*)(w + o * DD);
    float bias = b[o];
    float acc[QR];
    #pragma unroll
    for (int r = 0; r < QR; ++r) acc[r] = bias;
    #pragma unroll 8
    for (int kk = 0; kk < 64; ++kk){
        float4 u = wr[kk];
        #pragma unroll
        for (int r = 0; r < QR; ++r){
            const float* a = &se[r][kk * 4];
            acc[r] += u.x * a[0] + u.y * a[1] + u.z * a[2] + u.w * a[3];
        }
    }
    #pragma unroll
    for (int r = 0; r < QR; ++r) qkv[(n0 + r) * 768 + o] = acc[r];
}

// ---------------- K4: sparse masked attention, 1 wave per (node, head) ----------------
__global__ void k_attn(const float* __restrict__ qkv, const int* __restrict__ nbr,
                       const int* __restrict__ deg, float* __restrict__ ctx){
    __shared__ float sE[MAXD];
    __shared__ int   sM[MAXD];
    int n = blockIdx.x >> 3, h = blockIdx.x & 7;
    int dg = deg[n];
    if (dg == 0) return;                      // ctx unused for isolated nodes
    int lane = threadIdx.x;
    const float4* q4 = (const float4*)(qkv + n * 768 + h * 32);
    float4 qa[8];
    #pragma unroll
    for (int i = 0; i < 8; ++i) qa[i] = q4[i];

    float smax = -1e30f;
    for (int j = lane; j < dg; j += 64){
        int m = nbr[n * MAXD + j];
        const float4* k4 = (const float4*)(qkv + m * 768 + 256 + h * 32);
        float s = 0.f;
        #pragma unroll
        for (int i = 0; i < 8; ++i){
            float4 kv = k4[i];
            s += qa[i].x * kv.x + qa[i].y * kv.y + qa[i].z * kv.z + qa[i].w * kv.w;
        }
        s *= 0.17677669529663687f;            // 1/sqrt(32)
        sE[j] = s; sM[j] = m;
        smax = fmaxf(smax, s);
    }
    #pragma unroll
    for (int off = 32; off > 0; off >>= 1) smax = fmaxf(smax, __shfl_xor(smax, off));

    float sum = 0.f;
    for (int j = lane; j < dg; j += 64){ float e = expf(sE[j] - smax); sE[j] = e; sum += e; }
    #pragma unroll
    for (int off = 32; off > 0; off >>= 1) sum += __shfl_xor(sum, off);
    float inv = 1.0f / sum;
    __syncthreads();                          // fence: cross-lane sE/sM reads below

    int d = lane & 31, half = lane >> 5;
    float acc = 0.f;
    for (int j = half; j < dg; j += 2)
        acc += sE[j] * qkv[sM[j] * 768 + 512 + h * 32 + d];
    acc += __shfl_xor(acc, 32);
    if (lane < 32) ctx[n * 256 + h * 32 + d] = acc * inv;
}

// ---------------- K5: out-proj(+passthrough) -> Linear -> LayerNorm -> exact GELU, 8 nodes/block --
__global__ void k_final(const float* __restrict__ ctx, const float* __restrict__ emb,
                        const float* __restrict__ ow, const float* __restrict__ ob,
                        const float* __restrict__ lw, const float* __restrict__ lb,
                        const float* __restrict__ g, const float* __restrict__ beta,
                        const int* __restrict__ deg, float* __restrict__ out){
    __shared__ float xs[QR][DD];
    __shared__ float ys[QR][DD];
    __shared__ float stat[QR][2];
    int t = threadIdx.x;
    int n0 = blockIdx.x * QR;

    // stage ctx (zero for isolated nodes: avoids reading poisoned ws, proj result discarded)
    for (int i = t; i < QR * DD; i += 256){
        int r = i >> 8, c = i & 255, n = n0 + r;
        xs[r][c] = (deg[n] > 0) ? ctx[n * DD + c] : 0.f;
    }
    __syncthreads();

    // out-proj for all 8 nodes; passthrough select per node
    const float4* wr = (const float4*)(ow + t * DD);
    float ob_t = ob[t];
    float x[QR];
    #pragma unroll
    for (int r = 0; r < QR; ++r) x[r] = ob_t;
    #pragma unroll 8
    for (int kk = 0; kk < 64; ++kk){
        float4 u = wr[kk];
        #pragma unroll
        for (int r = 0; r < QR; ++r){
            const float* a = &xs[r][kk * 4];
            x[r] += u.x * a[0] + u.y * a[1] + u.z * a[2] + u.w * a[3];
        }
    }
    #pragma unroll
    for (int r = 0; r < QR; ++r)
        if (deg[n0 + r] == 0) x[r] = emb[(n0 + r) * DD + t];
    __syncthreads();                          // done reading xs (ctx)
    #pragma unroll
    for (int r = 0; r < QR; ++r) xs[r][t] = x[r];
    __syncthreads();

    // lin proj
    const float4* wr2 = (const float4*)(lw + t * DD);
    float lb_t = lb[t];
    float y[QR];
    #pragma unroll
    for (int r = 0; r < QR; ++r) y[r] = lb_t;
    #pragma unroll 8
    for (int kk = 0; kk < 64; ++kk){
        float4 u = wr2[kk];
        #pragma unroll
        for (int r = 0; r < QR; ++r){
            const float* a = &xs[r][kk * 4];
            y[r] += u.x * a[0] + u.y * a[1] + u.z * a[2] + u.w * a[3];
        }
    }
    #pragma unroll
    for (int r = 0; r < QR; ++r) ys[r][t] = y[r];
    __syncthreads();

    // per-node mean/var: 32-lane group per node (r = t>>5), 8 cols each
    {
        int r = t >> 5, c0 = t & 31;
        float s = 0.f, sq = 0.f;
        #pragma unroll
        for (int i = 0; i < 8; ++i){
            float v = ys[r][c0 + 32 * i];
            s += v; sq += v * v;
        }
        #pragma unroll
        for (int off = 16; off > 0; off >>= 1){
            s  += __shfl_xor(s,  off);
            sq += __shfl_xor(sq, off);
        }
        if (c0 == 0){ stat[r][0] = s; stat[r][1] = sq; }
    }
    __syncthreads();

    float g_t = g[t], be_t = beta[t];
    #pragma unroll
    for (int r = 0; r < QR; ++r){
        float mu  = stat[r][0] * (1.0f / 256.0f);
        float var = stat[r][1] * (1.0f / 256.0f) - mu * mu;
        float z = (y[r] - mu) * rsqrtf(fmaxf(var, 0.f) + 1e-5f);
        z = z * g_t + be_t;
        out[(n0 + r) * DD + t] = 0.5f * z * (1.0f + erff(z * 0.70710678118654752f));
    }
}

extern "C" void kernel_launch(void* const* d_in, const int* in_sizes, int n_in,
                              void* d_out, int out_size, void* d_ws, size_t ws_size,
                              hipStream_t stream){
    const float* emb = (const float*)d_in[0];
    const int*   ei  = (const int*)d_in[1];
    const float* ipw = (const float*)d_in[2];
    const float* ipb = (const float*)d_in[3];
    const float* ow  = (const float*)d_in[4];
    const float* ob  = (const float*)d_in[5];
    const float* lw  = (const float*)d_in[6];
    const float* lb  = (const float*)d_in[7];
    const float* g   = (const float*)d_in[8];
    const float* bet = (const float*)d_in[9];

    char* ws = (char*)d_ws;
    unsigned* adj = (unsigned*)(ws);                 // 4096*128*4  = 2 MiB
    int*      deg = (int*)(ws + 2097152);            // 16 KiB
    int*      nbr = (int*)(ws + 2113536);            // 4096*256*4 = 4 MiB
    float*    qkv = (float*)(ws + 6307840);          // 4096*768*4 = 12 MiB
    float*    ctx = (float*)(ws + 18890752);         // 4096*256*4 = 4 MiB

    hipMemsetAsync(adj, 0, 2097152, stream);
    k_edges<<<EE / 256, 256, 0, stream>>>(ei, adj);
    k_nbr  <<<NN, 64, 0, stream>>>(adj, nbr, deg);
    k_qkv  <<<dim3(3, NN / QR), 256, 0, stream>>>(emb, ipw, ipb, qkv);
    k_attn <<<NN * NH, 64, 0, stream>>>(qkv, nbr, deg, ctx);
    k_final<<<NN / QR, 256, 0, stream>>>(ctx, emb, ow, ob, lw, lb, g, bet, deg, (float*)d_out);
}

// Round 3
// 206.133 us; speedup vs baseline: 1.2175x; 1.2175x over previous
//
#include <hip/hip_runtime.h>
#include <math.h>

#define NN 4096
#define DD 256
#define EE 131072
#define MAXD 128

typedef __attribute__((ext_vector_type(8))) short short8;
typedef __attribute__((ext_vector_type(4))) float float4v;

__device__ __forceinline__ unsigned short f2bf(float f){
    unsigned u = __float_as_uint(f);
    return (unsigned short)((u + 0x7fffu + ((u >> 16) & 1u)) >> 16);   // RNE
}

// ---------------- K1: scatter edges into bitset (symmetric, no self) ----------------
__global__ void k_edges(const int* __restrict__ ei, unsigned* __restrict__ adj){
    int e = blockIdx.x * 256 + threadIdx.x;
    int s = ei[e];
    int d = ei[EE + e];
    if (s != d){
        atomicOr(&adj[s * 128 + (d >> 5)], 1u << (d & 31));
        atomicOr(&adj[d * 128 + (s >> 5)], 1u << (s & 31));
    }
}

// ---------------- K2: bitset -> compact neighbor list + degree (1 wave/node) ----------------
__global__ void k_nbr(const unsigned* __restrict__ adj, int* __restrict__ nbr, int* __restrict__ deg){
    int n = blockIdx.x;
    int lane = threadIdx.x;
    unsigned w0 = adj[n * 128 + 2 * lane];
    unsigned w1 = adj[n * 128 + 2 * lane + 1];
    int cnt = __popc(w0) + __popc(w1);
    int pre = cnt;
    #pragma unroll
    for (int off = 1; off < 64; off <<= 1){
        int t = __shfl_up(pre, off);
        if (lane >= off) pre += t;
    }
    int base = pre - cnt;
    int mb = lane * 64;
    while (w0){ int b = __ffs(w0) - 1; w0 &= w0 - 1u; if (base < MAXD) nbr[n * MAXD + base] = mb + b; base++; }
    mb += 32;
    while (w1){ int b = __ffs(w1) - 1; w1 &= w1 - 1u; if (base < MAXD) nbr[n * MAXD + base] = mb + b; base++; }
    if (lane == 63) deg[n] = (pre < MAXD) ? pre : MAXD;
}

// ---------------- generic fp32[rows][256] -> bf16 MFMA-fragment pack ----------------
// entry e: tile=e>>9, s=(e>>6)&7, lane=e&63; row=tile*16+(lane&15); k=s*32+(lane>>4)*8+j
__device__ __forceinline__ void pack_one(const float* __restrict__ src, unsigned short* __restrict__ dst, int e){
    int lane = e & 63;
    int row = ((e >> 9) << 4) + (lane & 15);
    int k0 = ((e >> 6) & 7) * 32 + ((lane >> 4) << 3);
    const float* p = src + row * DD + k0;
    short8 v;
    #pragma unroll
    for (int j = 0; j < 8; ++j) v[j] = (short)f2bf(p[j]);
    ((short8*)dst)[e] = v;
}

__global__ void k_pack(const float* __restrict__ src, unsigned short* __restrict__ dst){
    pack_one(src, dst, blockIdx.x * 256 + threadIdx.x);
}

__global__ void k_pack_w(const float* __restrict__ ipw, const float* __restrict__ ow, const float* __restrict__ lw,
                         unsigned short* __restrict__ bipw, unsigned short* __restrict__ bow, unsigned short* __restrict__ blw){
    int e = blockIdx.x * 256 + threadIdx.x;   // 40960 total
    if (e < 24576)       pack_one(ipw, bipw, e);
    else if (e < 32768)  pack_one(ow,  bow,  e - 24576);
    else                 pack_one(lw,  blw,  e - 32768);
}

// ---------------- K3: QKV GEMM, 16 nodes x 256 cols per block, MFMA ----------------
__global__ void __launch_bounds__(256) k_gqkv(const unsigned short* __restrict__ Ap, const unsigned short* __restrict__ Bp,
                                              const float* __restrict__ bias, float* __restrict__ qkv){
    int bx = blockIdx.x, by = blockIdx.y;
    int w = threadIdx.x >> 6, lane = threadIdx.x & 63;
    const short8* A8 = (const short8*)Ap;
    const short8* B8 = (const short8*)Bp;
    float4v acc[4];
    #pragma unroll
    for (int c = 0; c < 4; ++c) acc[c] = (float4v){0.f, 0.f, 0.f, 0.f};
    #pragma unroll
    for (int s = 0; s < 8; ++s){
        short8 a = A8[(bx * 8 + s) * 64 + lane];
        #pragma unroll
        for (int c = 0; c < 4; ++c){
            int to = by * 16 + w * 4 + c;
            short8 b = B8[(to * 8 + s) * 64 + lane];
            acc[c] = __builtin_amdgcn_mfma_f32_16x16x32_bf16(a, b, acc[c], 0, 0, 0);
        }
    }
    int q = lane >> 4, col = lane & 15;
    #pragma unroll
    for (int c = 0; c < 4; ++c){
        int o = (by * 16 + w * 4 + c) * 16 + col;
        float bo = bias[o];
        #pragma unroll
        for (int r = 0; r < 4; ++r)
            qkv[(bx * 16 + q * 4 + r) * 768 + o] = acc[c][r] + bo;
    }
}

// ---------------- K4: sparse masked attention, 2 heads per 128-thread block ----------------
__global__ void k_attn(const float* __restrict__ qkv, const int* __restrict__ nbr,
                       const int* __restrict__ deg, float* __restrict__ ctx){
    __shared__ float sE[2][MAXD];
    __shared__ int   sM[2][MAXD];
    int n = blockIdx.x >> 2;
    int dg = deg[n];
    if (dg == 0) return;
    int wv = threadIdx.x >> 6;
    int h = ((blockIdx.x & 3) << 1) | wv;
    int lane = threadIdx.x & 63;

    const float4* q4 = (const float4*)(qkv + n * 768 + h * 32);
    float4 qa[8];
    #pragma unroll
    for (int i = 0; i < 8; ++i) qa[i] = q4[i];

    float smax = -1e30f;
    for (int j = lane; j < dg; j += 64){
        int m = nbr[n * MAXD + j];
        const float4* k4 = (const float4*)(qkv + m * 768 + 256 + h * 32);
        float s = 0.f;
        #pragma unroll
        for (int i = 0; i < 8; ++i){
            float4 kv = k4[i];
            s += qa[i].x * kv.x + qa[i].y * kv.y + qa[i].z * kv.z + qa[i].w * kv.w;
        }
        s *= 0.17677669529663687f;            // 1/sqrt(32)
        sE[wv][j] = s; sM[wv][j] = m;
        smax = fmaxf(smax, s);
    }
    #pragma unroll
    for (int off = 32; off > 0; off >>= 1) smax = fmaxf(smax, __shfl_xor(smax, off));

    float sum = 0.f;
    for (int j = lane; j < dg; j += 64){ float e = expf(sE[wv][j] - smax); sE[wv][j] = e; sum += e; }
    #pragma unroll
    for (int off = 32; off > 0; off >>= 1) sum += __shfl_xor(sum, off);
    float inv = 1.0f / sum;
    __syncthreads();

    int d = lane & 31, half = lane >> 5;
    float acc = 0.f;
    for (int j = half; j < dg; j += 2)
        acc += sE[wv][j] * qkv[sM[wv][j] * 768 + 512 + h * 32 + d];
    acc += __shfl_xor(acc, 32);
    if (lane < 32) ctx[n * 256 + h * 32 + d] = acc * inv;
}

// ---------------- K5: out-proj MFMA + bias + passthrough-select -> bf16 A-pack ----------------
__global__ void __launch_bounds__(256) k_gow(const unsigned short* __restrict__ Ap, const unsigned short* __restrict__ Bp,
                                             const float* __restrict__ bias, const float* __restrict__ emb,
                                             const int* __restrict__ deg, unsigned short* __restrict__ Xp){
    __shared__ float xs[16][264];
    int bx = blockIdx.x;
    int w = threadIdx.x >> 6, lane = threadIdx.x & 63;
    const short8* A8 = (const short8*)Ap;
    const short8* B8 = (const short8*)Bp;
    float4v acc[4];
    #pragma unroll
    for (int c = 0; c < 4; ++c) acc[c] = (float4v){0.f, 0.f, 0.f, 0.f};
    #pragma unroll
    for (int s = 0; s < 8; ++s){
        short8 a = A8[(bx * 8 + s) * 64 + lane];
        #pragma unroll
        for (int c = 0; c < 4; ++c){
            int to = w * 4 + c;
            short8 b = B8[(to * 8 + s) * 64 + lane];
            acc[c] = __builtin_amdgcn_mfma_f32_16x16x32_bf16(a, b, acc[c], 0, 0, 0);
        }
    }
    int q = lane >> 4, col = lane & 15;
    #pragma unroll
    for (int c = 0; c < 4; ++c){
        int o = (w * 4 + c) * 16 + col;
        float bo = bias[o];
        #pragma unroll
        for (int r = 0; r < 4; ++r){
            int row = q * 4 + r, node = bx * 16 + row;
            float x = acc[c][r] + bo;
            if (deg[node] == 0) x = emb[node * DD + o];
            xs[row][o] = x;
        }
    }
    __syncthreads();
    #pragma unroll
    for (int pp = 0; pp < 2; ++pp){
        int e = threadIdx.x + pp * 256;          // 0..511
        int l2 = e & 63, s = e >> 6;
        int m = l2 & 15, k0 = s * 32 + ((l2 >> 4) << 3);
        short8 v;
        #pragma unroll
        for (int j = 0; j < 8; ++j) v[j] = (short)f2bf(xs[m][k0 + j]);
        ((short8*)Xp)[(bx * 8 + s) * 64 + l2] = v;
    }
}

// ---------------- K6: lin MFMA + bias -> LayerNorm -> exact GELU ----------------
__global__ void __launch_bounds__(256) k_glin(const unsigned short* __restrict__ Ap, const unsigned short* __restrict__ Bp,
                                              const float* __restrict__ bias, const float* __restrict__ g,
                                              const float* __restrict__ beta, float* __restrict__ out){
    __shared__ float ys[16][264];
    __shared__ float gs[DD], bs[DD];
    __shared__ float stat[16][2];
    int bx = blockIdx.x;
    int t = threadIdx.x;
    int w = t >> 6, lane = t & 63;
    gs[t] = g[t]; bs[t] = beta[t];
    const short8* A8 = (const short8*)Ap;
    const short8* B8 = (const short8*)Bp;
    float4v acc[4];
    #pragma unroll
    for (int c = 0; c < 4; ++c) acc[c] = (float4v){0.f, 0.f, 0.f, 0.f};
    #pragma unroll
    for (int s = 0; s < 8; ++s){
        short8 a = A8[(bx * 8 + s) * 64 + lane];
        #pragma unroll
        for (int c = 0; c < 4; ++c){
            int to = w * 4 + c;
            short8 b = B8[(to * 8 + s) * 64 + lane];
            acc[c] = __builtin_amdgcn_mfma_f32_16x16x32_bf16(a, b, acc[c], 0, 0, 0);
        }
    }
    int q = lane >> 4, col = lane & 15;
    #pragma unroll
    for (int c = 0; c < 4; ++c){
        int o = (w * 4 + c) * 16 + col;
        float bo = bias[o];
        #pragma unroll
        for (int r = 0; r < 4; ++r)
            ys[q * 4 + r][o] = acc[c][r] + bo;
    }
    __syncthreads();
    int r = t >> 4, i = t & 15;
    float s1 = 0.f, s2 = 0.f;
    #pragma unroll
    for (int jj = 0; jj < 16; ++jj){ float v = ys[r][i + 16 * jj]; s1 += v; s2 += v * v; }
    #pragma unroll
    for (int off = 8; off > 0; off >>= 1){ s1 += __shfl_xor(s1, off); s2 += __shfl_xor(s2, off); }
    if (i == 0){
        float mu = s1 * (1.0f / 256.0f);
        float var = s2 * (1.0f / 256.0f) - mu * mu;
        stat[r][0] = mu;
        stat[r][1] = rsqrtf(fmaxf(var, 0.f) + 1e-5f);
    }
    __syncthreads();
    float mu = stat[r][0], rs = stat[r][1];
    int nbase = (bx * 16 + r) * DD;
    #pragma unroll
    for (int jj = 0; jj < 16; ++jj){
        int cc = i + 16 * jj;
        float z = (ys[r][cc] - mu) * rs * gs[cc] + bs[cc];
        out[nbase + cc] = 0.5f * z * (1.0f + erff(z * 0.70710678118654752f));
    }
}

extern "C" void kernel_launch(void* const* d_in, const int* in_sizes, int n_in,
                              void* d_out, int out_size, void* d_ws, size_t ws_size,
                              hipStream_t stream){
    const float* emb = (const float*)d_in[0];
    const int*   ei  = (const int*)d_in[1];
    const float* ipw = (const float*)d_in[2];
    const float* ipb = (const float*)d_in[3];
    const float* ow  = (const float*)d_in[4];
    const float* ob  = (const float*)d_in[5];
    const float* lw  = (const float*)d_in[6];
    const float* lb  = (const float*)d_in[7];
    const float* g   = (const float*)d_in[8];
    const float* bet = (const float*)d_in[9];

    char* ws = (char*)d_ws;
    // region reuse (stream-serial): adj region also hosts weight packs (after k_nbr);
    // qkv region hosts ctx-pack + x-pack (after k_attn); ctx region hosts emb A-pack (until k_gqkv done)
    unsigned*       adj  = (unsigned*)(ws);                    // @0, 2 MiB (dead after k_nbr)
    unsigned short* bipw = (unsigned short*)(ws);              // @0, 384 KiB
    unsigned short* bow  = (unsigned short*)(ws + 393216);     // 128 KiB
    unsigned short* blw  = (unsigned short*)(ws + 524288);     // 128 KiB
    int*            deg  = (int*)(ws + 2097152);               // 16 KiB
    int*            nbr  = (int*)(ws + 2162688);               // 2 MiB (MAXD=128)
    float*          qkv  = (float*)(ws + 4259840);             // 12 MiB (dead after k_attn)
    unsigned short* cpk  = (unsigned short*)(ws + 4259840);    // 2 MiB (ctx pack, after attn)
    unsigned short* xpk  = (unsigned short*)(ws + 6356992);    // 2 MiB (x pack)
    float*          ctx  = (float*)(ws + 16842752);            // 4 MiB
    unsigned short* apk  = (unsigned short*)(ws + 16842752);   // 2 MiB (emb pack, dead before attn writes ctx)

    hipMemsetAsync(adj, 0, 2097152, stream);
    k_edges <<<EE / 256, 256, 0, stream>>>(ei, adj);
    k_nbr   <<<NN, 64, 0, stream>>>(adj, nbr, deg);
    k_pack  <<<512, 256, 0, stream>>>(emb, apk);
    k_pack_w<<<160, 256, 0, stream>>>(ipw, ow, lw, bipw, bow, blw);
    k_gqkv  <<<dim3(256, 3), 256, 0, stream>>>(apk, bipw, ipb, qkv);
    k_attn  <<<NN * 4, 128, 0, stream>>>(qkv, nbr, deg, ctx);
    k_pack  <<<512, 256, 0, stream>>>(ctx, cpk);
    k_gow   <<<256, 256, 0, stream>>>(cpk, bow, ob, emb, deg, xpk);
    k_glin  <<<256, 256, 0, stream>>>(xpk, blw, lb, g, bet, (float*)d_out);
}

// Round 4
// 158.937 us; speedup vs baseline: 1.5790x; 1.2969x over previous
//
#include <hip/hip_runtime.h>
#include <math.h>

#define NN 4096
#define DD 256
#define EE 131072
#define MAXD 192

typedef __attribute__((ext_vector_type(8))) short short8;
typedef __attribute__((ext_vector_type(4))) float float4v;

__device__ __forceinline__ unsigned short f2bf(float f){
    unsigned u = __float_as_uint(f);
    return (unsigned short)((u + 0x7fffu + ((u >> 16) & 1u)) >> 16);   // RNE
}

// ---------------- K1: scatter edges into bitset (symmetric, no self) ----------------
__global__ void k_edges(const int* __restrict__ ei, unsigned* __restrict__ adj){
    int e = blockIdx.x * 256 + threadIdx.x;
    int s = ei[e];
    int d = ei[EE + e];
    if (s != d){
        atomicOr(&adj[s * 128 + (d >> 5)], 1u << (d & 31));
        atomicOr(&adj[d * 128 + (s >> 5)], 1u << (s & 31));
    }
}

// ---------------- fp32[rows][256] -> bf16 MFMA-fragment pack ----------------
// entry e: tile=e>>9, s=(e>>6)&7, lane=e&63; row=tile*16+(lane&15); k=s*32+(lane>>4)*8+j
__device__ __forceinline__ void pack_one(const float* __restrict__ src, unsigned short* __restrict__ dst, int e){
    int lane = e & 63;
    int row = ((e >> 9) << 4) + (lane & 15);
    int k0 = ((e >> 6) & 7) * 32 + ((lane >> 4) << 3);
    const float* p = src + row * DD + k0;
    short8 v;
    #pragma unroll
    for (int j = 0; j < 8; ++j) v[j] = (short)f2bf(p[j]);
    ((short8*)dst)[e] = v;
}

// one kernel packs emb + all three weights
__global__ void k_packall(const float* __restrict__ emb, const float* __restrict__ ipw,
                          const float* __restrict__ ow, const float* __restrict__ lw,
                          unsigned short* __restrict__ apk, unsigned short* __restrict__ bipw,
                          unsigned short* __restrict__ bow, unsigned short* __restrict__ blw){
    int e = blockIdx.x * 256 + threadIdx.x;       // 172032 total
    if (e < 131072)       pack_one(emb, apk, e);
    else if (e < 155648)  pack_one(ipw, bipw, e - 131072);
    else if (e < 163840)  pack_one(ow,  bow,  e - 155648);
    else                  pack_one(lw,  blw,  e - 163840);
}

// ---------------- K3: QKV GEMM, 16 nodes x 256 cols per block, MFMA ----------------
__global__ void __launch_bounds__(256) k_gqkv(const unsigned short* __restrict__ Ap, const unsigned short* __restrict__ Bp,
                                              const float* __restrict__ bias, float* __restrict__ qkv){
    int bx = blockIdx.x, by = blockIdx.y;
    int w = threadIdx.x >> 6, lane = threadIdx.x & 63;
    const short8* A8 = (const short8*)Ap;
    const short8* B8 = (const short8*)Bp;
    float4v acc[4];
    #pragma unroll
    for (int c = 0; c < 4; ++c) acc[c] = (float4v){0.f, 0.f, 0.f, 0.f};
    #pragma unroll
    for (int s = 0; s < 8; ++s){
        short8 a = A8[(bx * 8 + s) * 64 + lane];
        #pragma unroll
        for (int c = 0; c < 4; ++c){
            int to = by * 16 + w * 4 + c;
            short8 b = B8[(to * 8 + s) * 64 + lane];
            acc[c] = __builtin_amdgcn_mfma_f32_16x16x32_bf16(a, b, acc[c], 0, 0, 0);
        }
    }
    int q = lane >> 4, col = lane & 15;
    #pragma unroll
    for (int c = 0; c < 4; ++c){
        int o = (by * 16 + w * 4 + c) * 16 + col;
        float bo = bias[o];
        #pragma unroll
        for (int r = 0; r < 4; ++r)
            qkv[(bx * 16 + q * 4 + r) * 768 + o] = acc[c][r] + bo;
    }
}

// ---------------- K4: attention, one 256-thread block per node ----------------
// nbr extraction from adj + scores + softmax + values + fused bf16 A-pack write
__global__ void __launch_bounds__(256) k_attn(const float* __restrict__ qkv, const unsigned* __restrict__ adj,
                                              int* __restrict__ deg, unsigned short* __restrict__ cpk){
    __shared__ float sQ[DD];
    __shared__ float sS[8][MAXD];
    __shared__ int   sNbr[MAXD];
    __shared__ int   sW0, sDeg;
    int n = blockIdx.x, t = threadIdx.x;
    int lane = t & 63;

    sQ[t] = qkv[n * 768 + t];                 // issue early

    // --- neighbor extraction (threads 0..127 hold words; waves 2,3 idle) ---
    unsigned wbits = 0; int c = 0;
    if (t < 128){ wbits = adj[n * 128 + t]; c = __popc(wbits); }
    int pre = c;
    #pragma unroll
    for (int off = 1; off < 64; off <<= 1){
        int tmp = __shfl_up(pre, off);
        if (lane >= off) pre += tmp;
    }
    if (t == 63) sW0 = pre;
    __syncthreads();
    if (t < 128){
        int base = pre - c + ((t >= 64) ? sW0 : 0);
        int mb = t * 32;
        while (wbits){
            int b = __ffs(wbits) - 1; wbits &= wbits - 1u;
            if (base < MAXD) sNbr[base] = mb + b;
            base++;
        }
        if (t == 127){
            int dtot = pre + sW0;
            if (dtot > MAXD) dtot = MAXD;
            sDeg = dtot;
            deg[n] = dtot;
        }
    }
    __syncthreads();
    int dg = sDeg;
    if (dg == 0) return;                      // uniform exit; deg already written

    // --- scores: j = t>>3 (+32 stride), p = t&7 covers 4 dims per head ---
    int j0 = t >> 3, p = t & 7;
    float4 qp[8];
    #pragma unroll
    for (int h = 0; h < 8; ++h) qp[h] = ((const float4*)sQ)[h * 8 + p];
    for (int j = j0; j < dg; j += 32){
        const float4* kb = (const float4*)(qkv + sNbr[j] * 768 + 256);
        #pragma unroll
        for (int h = 0; h < 8; ++h){
            float4 kv = kb[h * 8 + p];
            float s = qp[h].x * kv.x + qp[h].y * kv.y + qp[h].z * kv.z + qp[h].w * kv.w;
            s += __shfl_xor(s, 1); s += __shfl_xor(s, 2); s += __shfl_xor(s, 4);
            if (p == 0) sS[h][j] = s * 0.17677669529663687f;   // 1/sqrt(32)
        }
    }
    __syncthreads();

    // --- softmax per head: 32-lane group h = t>>5 ---
    int h = t >> 5, l = t & 31;
    float m1 = -1e30f;
    for (int j = l; j < dg; j += 32) m1 = fmaxf(m1, sS[h][j]);
    #pragma unroll
    for (int off = 16; off > 0; off >>= 1) m1 = fmaxf(m1, __shfl_xor(m1, off));
    float sum = 0.f;
    for (int j = l; j < dg; j += 32){ float e = __expf(sS[h][j] - m1); sS[h][j] = e; sum += e; }
    #pragma unroll
    for (int off = 16; off > 0; off >>= 1) sum += __shfl_xor(sum, off);
    float inv = 1.0f / sum;
    __syncthreads();                          // sS now holds exp weights

    // --- values: thread t = (h = t>>5, d = t&31); coalesced 1KB row per neighbor ---
    float O = 0.f;
    int j = 0;
    for (; j + 4 <= dg; j += 4){
        int m0 = sNbr[j], m1_ = sNbr[j + 1], m2 = sNbr[j + 2], m3 = sNbr[j + 3];
        float v0 = qkv[m0 * 768 + 512 + t];
        float v1 = qkv[m1_ * 768 + 512 + t];
        float v2 = qkv[m2 * 768 + 512 + t];
        float v3 = qkv[m3 * 768 + 512 + t];
        O += sS[h][j] * v0 + sS[h][j + 1] * v1 + sS[h][j + 2] * v2 + sS[h][j + 3] * v3;
    }
    for (; j < dg; ++j) O += sS[h][j] * qkv[sNbr[j] * 768 + 512 + t];
    O *= inv;

    // --- fused pack: ctx[n][t] -> bf16 A-fragment slot ---
    int s  = t >> 5;                          // k-slice
    int l2 = (((t >> 3) & 3) * 16) + (n & 15);
    int idx = ((((n >> 4) * 8) + s) * 64 + l2) * 8 + (t & 7);
    cpk[idx] = f2bf(O);
}

// ---------------- K5: out-proj MFMA + bias + passthrough-select -> bf16 A-pack ----------------
__global__ void __launch_bounds__(256) k_gow(const unsigned short* __restrict__ Ap, const unsigned short* __restrict__ Bp,
                                             const float* __restrict__ bias, const float* __restrict__ emb,
                                             const int* __restrict__ deg, unsigned short* __restrict__ Xp){
    __shared__ float xs[16][264];
    int bx = blockIdx.x;
    int w = threadIdx.x >> 6, lane = threadIdx.x & 63;
    const short8* A8 = (const short8*)Ap;
    const short8* B8 = (const short8*)Bp;
    float4v acc[4];
    #pragma unroll
    for (int c = 0; c < 4; ++c) acc[c] = (float4v){0.f, 0.f, 0.f, 0.f};
    #pragma unroll
    for (int s = 0; s < 8; ++s){
        short8 a = A8[(bx * 8 + s) * 64 + lane];
        #pragma unroll
        for (int c = 0; c < 4; ++c){
            int to = w * 4 + c;
            short8 b = B8[(to * 8 + s) * 64 + lane];
            acc[c] = __builtin_amdgcn_mfma_f32_16x16x32_bf16(a, b, acc[c], 0, 0, 0);
        }
    }
    int q = lane >> 4, col = lane & 15;
    #pragma unroll
    for (int c = 0; c < 4; ++c){
        int o = (w * 4 + c) * 16 + col;
        float bo = bias[o];
        #pragma unroll
        for (int r = 0; r < 4; ++r){
            int row = q * 4 + r, node = bx * 16 + row;
            float x = acc[c][r] + bo;
            if (deg[node] == 0) x = emb[node * DD + o];
            xs[row][o] = x;
        }
    }
    __syncthreads();
    #pragma unroll
    for (int pp = 0; pp < 2; ++pp){
        int e = threadIdx.x + pp * 256;          // 0..511
        int l2 = e & 63, s = e >> 6;
        int m = l2 & 15, k0 = s * 32 + ((l2 >> 4) << 3);
        short8 v;
        #pragma unroll
        for (int j = 0; j < 8; ++j) v[j] = (short)f2bf(xs[m][k0 + j]);
        ((short8*)Xp)[(bx * 8 + s) * 64 + l2] = v;
    }
}

// ---------------- K6: lin MFMA + bias -> LayerNorm -> exact GELU ----------------
__global__ void __launch_bounds__(256) k_glin(const unsigned short* __restrict__ Ap, const unsigned short* __restrict__ Bp,
                                              const float* __restrict__ bias, const float* __restrict__ g,
                                              const float* __restrict__ beta, float* __restrict__ out){
    __shared__ float ys[16][264];
    __shared__ float gs[DD], bs[DD];
    __shared__ float stat[16][2];
    int bx = blockIdx.x;
    int t = threadIdx.x;
    int w = t >> 6, lane = t & 63;
    gs[t] = g[t]; bs[t] = beta[t];
    const short8* A8 = (const short8*)Ap;
    const short8* B8 = (const short8*)Bp;
    float4v acc[4];
    #pragma unroll
    for (int c = 0; c < 4; ++c) acc[c] = (float4v){0.f, 0.f, 0.f, 0.f};
    #pragma unroll
    for (int s = 0; s < 8; ++s){
        short8 a = A8[(bx * 8 + s) * 64 + lane];
        #pragma unroll
        for (int c = 0; c < 4; ++c){
            int to = w * 4 + c;
            short8 b = B8[(to * 8 + s) * 64 + lane];
            acc[c] = __builtin_amdgcn_mfma_f32_16x16x32_bf16(a, b, acc[c], 0, 0, 0);
        }
    }
    int q = lane >> 4, col = lane & 15;
    #pragma unroll
    for (int c = 0; c < 4; ++c){
        int o = (w * 4 + c) * 16 + col;
        float bo = bias[o];
        #pragma unroll
        for (int r = 0; r < 4; ++r)
            ys[q * 4 + r][o] = acc[c][r] + bo;
    }
    __syncthreads();
    int r = t >> 4, i = t & 15;
    float s1 = 0.f, s2 = 0.f;
    #pragma unroll
    for (int jj = 0; jj < 16; ++jj){ float v = ys[r][i + 16 * jj]; s1 += v; s2 += v * v; }
    #pragma unroll
    for (int off = 8; off > 0; off >>= 1){ s1 += __shfl_xor(s1, off); s2 += __shfl_xor(s2, off); }
    if (i == 0){
        float mu = s1 * (1.0f / 256.0f);
        float var = s2 * (1.0f / 256.0f) - mu * mu;
        stat[r][0] = mu;
        stat[r][1] = rsqrtf(fmaxf(var, 0.f) + 1e-5f);
    }
    __syncthreads();
    float mu = stat[r][0], rs = stat[r][1];
    int nbase = (bx * 16 + r) * DD;
    #pragma unroll
    for (int jj = 0; jj < 16; ++jj){
        int cc = i + 16 * jj;
        float z = (ys[r][cc] - mu) * rs * gs[cc] + bs[cc];
        out[nbase + cc] = 0.5f * z * (1.0f + erff(z * 0.70710678118654752f));
    }
}

extern "C" void kernel_launch(void* const* d_in, const int* in_sizes, int n_in,
                              void* d_out, int out_size, void* d_ws, size_t ws_size,
                              hipStream_t stream){
    const float* emb = (const float*)d_in[0];
    const int*   ei  = (const int*)d_in[1];
    const float* ipw = (const float*)d_in[2];
    const float* ipb = (const float*)d_in[3];
    const float* ow  = (const float*)d_in[4];
    const float* ob  = (const float*)d_in[5];
    const float* lw  = (const float*)d_in[6];
    const float* lb  = (const float*)d_in[7];
    const float* g   = (const float*)d_in[8];
    const float* bet = (const float*)d_in[9];

    char* ws = (char*)d_ws;
    unsigned*       adj  = (unsigned*)(ws);                    // 2 MiB (live through k_attn)
    int*            deg  = (int*)(ws + 2097152);               // 16 KiB
    unsigned short* bipw = (unsigned short*)(ws + 2113536);    // 384 KiB
    unsigned short* bow  = (unsigned short*)(ws + 2506752);    // 128 KiB
    unsigned short* blw  = (unsigned short*)(ws + 2637824);    // 128 KiB
    unsigned short* apk  = (unsigned short*)(ws + 2768896);    // 2 MiB
    float*          qkv  = (float*)(ws + 4866048);             // 12 MiB
    unsigned short* cpk  = (unsigned short*)(ws + 17448960);   // 2 MiB
    unsigned short* xpk  = (unsigned short*)(ws + 19546112);   // 2 MiB

    hipMemsetAsync(adj, 0, 2097152, stream);
    k_edges  <<<EE / 256, 256, 0, stream>>>(ei, adj);
    k_packall<<<672, 256, 0, stream>>>(emb, ipw, ow, lw, apk, bipw, bow, blw);
    k_gqkv   <<<dim3(256, 3), 256, 0, stream>>>(apk, bipw, ipb, qkv);
    k_attn   <<<NN, 256, 0, stream>>>(qkv, adj, deg, cpk);
    k_gow    <<<256, 256, 0, stream>>>(cpk, bow, ob, emb, deg, xpk);
    k_glin   <<<256, 256, 0, stream>>>(xpk, blw, lb, g, bet, (float*)d_out);
}

// Round 5
// 158.300 us; speedup vs baseline: 1.5854x; 1.0040x over previous
//
#include <hip/hip_runtime.h>
#include <math.h>

#define NN 4096
#define DD 256
#define EE 131072
#define MAXD 192

typedef __attribute__((ext_vector_type(8))) short short8;
typedef __attribute__((ext_vector_type(4))) float float4v;

__device__ __forceinline__ unsigned short f2bf(float f){
    unsigned u = __float_as_uint(f);
    return (unsigned short)((u + 0x7fffu + ((u >> 16) & 1u)) >> 16);   // RNE
}
__device__ __forceinline__ float blo(unsigned u){ return __uint_as_float(u << 16); }
__device__ __forceinline__ float bhi(unsigned u){ return __uint_as_float(u & 0xffff0000u); }

// ---------------- K1: pack weights to MFMA fragments + zero adj ----------------
// entry e: tile=e>>9, s=(e>>6)&7, lane=e&63; row=tile*16+(lane&15); k=s*32+(lane>>4)*8+j
__device__ __forceinline__ void pack_one(const float* __restrict__ src, unsigned short* __restrict__ dst, int e){
    int lane = e & 63;
    int row = ((e >> 9) << 4) + (lane & 15);
    int k0 = ((e >> 6) & 7) * 32 + ((lane >> 4) << 3);
    const float* p = src + row * DD + k0;
    short8 v;
    #pragma unroll
    for (int j = 0; j < 8; ++j) v[j] = (short)f2bf(p[j]);
    ((short8*)dst)[e] = v;
}

__global__ void k_packw(const float* __restrict__ ipw, const float* __restrict__ ow, const float* __restrict__ lw,
                        unsigned short* __restrict__ bipw, unsigned short* __restrict__ bow,
                        unsigned short* __restrict__ blw, unsigned* __restrict__ adj){
    int e = blockIdx.x * 256 + threadIdx.x;       // 40960 threads
    for (int i = e; i < 524288; i += 40960) adj[i] = 0u;   // zero 2MB adj (replaces memset dispatch)
    if (e < 24576)       pack_one(ipw, bipw, e);
    else if (e < 32768)  pack_one(ow,  bow,  e - 24576);
    else                 pack_one(lw,  blw,  e - 32768);
}

// ---------------- K2: scatter edges into bitset (symmetric, no self) ----------------
__global__ void k_edges(const int* __restrict__ ei, unsigned* __restrict__ adj){
    int e = blockIdx.x * 256 + threadIdx.x;
    int s = ei[e];
    int d = ei[EE + e];
    if (s != d){
        atomicOr(&adj[s * 128 + (d >> 5)], 1u << (d & 31));
        atomicOr(&adj[d * 128 + (s >> 5)], 1u << (s & 31));
    }
}

// ---------------- K3: QKV GEMM; A built in-kernel from emb; Q fp32, K/V bf16 ----------------
__global__ void __launch_bounds__(256) k_gqkv(const float* __restrict__ emb, const unsigned short* __restrict__ Bp,
                                              const float* __restrict__ bias, float* __restrict__ qf,
                                              unsigned short* __restrict__ kb, unsigned short* __restrict__ vb){
    __shared__ float sA[16 * 260];
    int bx = blockIdx.x, by = blockIdx.y;
    int t = threadIdx.x, w = t >> 6, lane = t & 63;
    #pragma unroll
    for (int i = 0; i < 16; ++i)
        sA[i * 260 + t] = emb[(bx * 16 + i) * 256 + t];
    __syncthreads();

    int arow = lane & 15, ak0 = (lane >> 4) << 3;
    short8 af[8];
    #pragma unroll
    for (int s = 0; s < 8; ++s){
        const float* p = &sA[arow * 260 + s * 32 + ak0];
        #pragma unroll
        for (int j = 0; j < 8; ++j) af[s][j] = (short)f2bf(p[j]);
    }

    const short8* B8 = (const short8*)Bp;
    float4v acc[4];
    #pragma unroll
    for (int c = 0; c < 4; ++c) acc[c] = (float4v){0.f, 0.f, 0.f, 0.f};
    #pragma unroll
    for (int s = 0; s < 8; ++s){
        #pragma unroll
        for (int c = 0; c < 4; ++c){
            int to = by * 16 + w * 4 + c;
            acc[c] = __builtin_amdgcn_mfma_f32_16x16x32_bf16(af[s], B8[(to * 8 + s) * 64 + lane], acc[c], 0, 0, 0);
        }
    }
    int q = lane >> 4, col = lane & 15;
    #pragma unroll
    for (int c = 0; c < 4; ++c){
        int o = (w * 4 + c) * 16 + col;
        float bo = bias[by * 256 + o];
        #pragma unroll
        for (int r = 0; r < 4; ++r){
            int node = bx * 16 + q * 4 + r;
            float val = acc[c][r] + bo;
            if (by == 0)      qf[node * 256 + o] = val;
            else if (by == 1) kb[node * 256 + o] = f2bf(val);
            else              vb[node * 256 + o] = f2bf(val);
        }
    }
}

// ---------------- K4: attention, one 256-thread block per node; bf16 K/V ----------------
__global__ void __launch_bounds__(256) k_attn(const float* __restrict__ qf, const unsigned short* __restrict__ kb,
                                              const unsigned short* __restrict__ vb, const unsigned* __restrict__ adj,
                                              int* __restrict__ deg, unsigned short* __restrict__ cpk){
    __shared__ float sQ[DD];
    __shared__ float sS[8][MAXD];
    __shared__ int   sNbr[MAXD];
    __shared__ float sInv[8];
    __shared__ float sRed[128][2];
    __shared__ int   sW0, sDeg;
    int n = blockIdx.x, t = threadIdx.x;
    int lane = t & 63;

    sQ[t] = qf[n * 256 + t];

    // --- neighbor extraction (threads 0..127 hold adj words) ---
    unsigned wbits = 0; int c = 0;
    if (t < 128){ wbits = adj[n * 128 + t]; c = __popc(wbits); }
    int pre = c;
    #pragma unroll
    for (int off = 1; off < 64; off <<= 1){
        int tmp = __shfl_up(pre, off);
        if (lane >= off) pre += tmp;
    }
    if (t == 63) sW0 = pre;
    __syncthreads();
    if (t < 128){
        int base = pre - c + ((t >= 64) ? sW0 : 0);
        int mb = t * 32;
        while (wbits){
            int b = __ffs(wbits) - 1; wbits &= wbits - 1u;
            if (base < MAXD) sNbr[base] = mb + b;
            base++;
        }
        if (t == 127){
            int dtot = pre + sW0;
            if (dtot > MAXD) dtot = MAXD;
            sDeg = dtot;
            deg[n] = dtot;
        }
    }
    __syncthreads();
    int dg = sDeg;
    if (dg == 0) return;

    // --- scores: j = t>>3 (+32 stride), p = t&7 covers 4 dims per head ---
    int j0 = t >> 3, p = t & 7;
    float4 qp[8];
    #pragma unroll
    for (int h = 0; h < 8; ++h) qp[h] = ((const float4*)sQ)[h * 8 + p];
    for (int j = j0; j < dg; j += 32){
        const uint2* kr = (const uint2*)(kb + sNbr[j] * 256);
        #pragma unroll
        for (int h = 0; h < 8; ++h){
            uint2 kv = kr[h * 8 + p];
            float s = qp[h].x * blo(kv.x) + qp[h].y * bhi(kv.x)
                    + qp[h].z * blo(kv.y) + qp[h].w * bhi(kv.y);
            s += __shfl_xor(s, 1); s += __shfl_xor(s, 2); s += __shfl_xor(s, 4);
            if (p == 0) sS[h][j] = s * 0.17677669529663687f;   // 1/sqrt(32)
        }
    }
    __syncthreads();

    // --- softmax per head: 32-lane group h = t>>5 ---
    int h = t >> 5, l = t & 31;
    float m1 = -1e30f;
    for (int j = l; j < dg; j += 32) m1 = fmaxf(m1, sS[h][j]);
    #pragma unroll
    for (int off = 16; off > 0; off >>= 1) m1 = fmaxf(m1, __shfl_xor(m1, off));
    float sum = 0.f;
    for (int j = l; j < dg; j += 32){ float e = __expf(sS[h][j] - m1); sS[h][j] = e; sum += e; }
    #pragma unroll
    for (int off = 16; off > 0; off >>= 1) sum += __shfl_xor(sum, off);
    if (l == 0) sInv[h] = 1.0f / sum;
    __syncthreads();

    // --- values: pair = t>>7 handles j%2==pair; idx = t&127 covers dims 2idx,2idx+1 ---
    int pair = t >> 7, idx = t & 127, h2 = idx >> 4;
    const uint* vb32 = (const uint*)vb;
    float O0 = 0.f, O1 = 0.f;
    for (int j = pair; j < dg; j += 2){
        unsigned u = vb32[sNbr[j] * 128 + idx];
        float wgt = sS[h2][j];
        O0 += wgt * blo(u);
        O1 += wgt * bhi(u);
    }
    if (pair){ sRed[idx][0] = O0; sRed[idx][1] = O1; }
    __syncthreads();
    if (!pair){
        float inv = sInv[h2];
        O0 = (O0 + sRed[idx][0]) * inv;
        O1 = (O1 + sRed[idx][1]) * inv;
        // fused bf16 A-fragment pack of ctx, dword-wide (dims d=2*idx, d+1)
        int d = idx * 2;
        int s  = d >> 5;
        int l2 = ((d >> 3) & 3) * 16 + (n & 15);
        unsigned packed = (unsigned)f2bf(O0) | ((unsigned)f2bf(O1) << 16);
        ((unsigned*)cpk)[(((n >> 4) * 8 + s) * 64 + l2) * 4 + ((d & 7) >> 1)] = packed;
    }
}

// ---------------- K5: out-proj + passthrough -> (LDS pack) -> lin -> LayerNorm -> GELU ----------------
__global__ void __launch_bounds__(256) k_tail(const unsigned short* __restrict__ Ap, const unsigned short* __restrict__ Bow,
                                              const float* __restrict__ ob, const float* __restrict__ emb,
                                              const int* __restrict__ deg, const unsigned short* __restrict__ Blw,
                                              const float* __restrict__ lb, const float* __restrict__ g,
                                              const float* __restrict__ beta, float* __restrict__ out){
    __shared__ float xs[16 * 264];
    __shared__ short8 sPk[512];
    __shared__ float stat[16][2];
    int bx = blockIdx.x, t = threadIdx.x;
    int w = t >> 6, lane = t & 63;
    const short8* A8 = (const short8*)Ap;
    const short8* B8 = (const short8*)Bow;

    float4v acc[4];
    #pragma unroll
    for (int c = 0; c < 4; ++c) acc[c] = (float4v){0.f, 0.f, 0.f, 0.f};
    #pragma unroll
    for (int s = 0; s < 8; ++s){
        short8 a = A8[(bx * 8 + s) * 64 + lane];
        #pragma unroll
        for (int c = 0; c < 4; ++c)
            acc[c] = __builtin_amdgcn_mfma_f32_16x16x32_bf16(a, B8[((w * 4 + c) * 8 + s) * 64 + lane], acc[c], 0, 0, 0);
    }
    int q = lane >> 4, col = lane & 15;
    #pragma unroll
    for (int c = 0; c < 4; ++c){
        int o = (w * 4 + c) * 16 + col;
        float bo = ob[o];
        #pragma unroll
        for (int r = 0; r < 4; ++r){
            int row = q * 4 + r, node = bx * 16 + row;
            float x = acc[c][r] + bo;
            if (deg[node] == 0) x = emb[node * 256 + o];
            xs[row * 264 + o] = x;
        }
    }
    __syncthreads();

    // pack x -> bf16 fragments in LDS
    #pragma unroll
    for (int pp = 0; pp < 2; ++pp){
        int e = t + pp * 256;
        int l2 = e & 63, s = e >> 6;
        int m = l2 & 15, k0 = s * 32 + ((l2 >> 4) << 3);
        short8 v;
        #pragma unroll
        for (int j = 0; j < 8; ++j) v[j] = (short)f2bf(xs[m * 264 + k0 + j]);
        sPk[e] = v;
    }
    __syncthreads();

    // lin MFMA
    const short8* B2 = (const short8*)Blw;
    float4v acc2[4];
    #pragma unroll
    for (int c = 0; c < 4; ++c) acc2[c] = (float4v){0.f, 0.f, 0.f, 0.f};
    #pragma unroll
    for (int s = 0; s < 8; ++s){
        short8 a = sPk[s * 64 + lane];
        #pragma unroll
        for (int c = 0; c < 4; ++c)
            acc2[c] = __builtin_amdgcn_mfma_f32_16x16x32_bf16(a, B2[((w * 4 + c) * 8 + s) * 64 + lane], acc2[c], 0, 0, 0);
    }
    __syncthreads();                 // xs reads done; reuse as ys
    #pragma unroll
    for (int c = 0; c < 4; ++c){
        int o = (w * 4 + c) * 16 + col;
        float bo = lb[o];
        #pragma unroll
        for (int r = 0; r < 4; ++r)
            xs[(q * 4 + r) * 264 + o] = acc2[c][r] + bo;
    }
    __syncthreads();

    // LayerNorm + exact GELU
    int rr = t >> 4, i = t & 15;
    float s1 = 0.f, s2 = 0.f;
    #pragma unroll
    for (int jj = 0; jj < 16; ++jj){ float v = xs[rr * 264 + i + 16 * jj]; s1 += v; s2 += v * v; }
    #pragma unroll
    for (int off = 8; off > 0; off >>= 1){ s1 += __shfl_xor(s1, off); s2 += __shfl_xor(s2, off); }
    if (i == 0){
        float mu = s1 * (1.0f / 256.0f);
        float var = s2 * (1.0f / 256.0f) - mu * mu;
        stat[rr][0] = mu;
        stat[rr][1] = rsqrtf(fmaxf(var, 0.f) + 1e-5f);
    }
    __syncthreads();
    float mu = stat[rr][0], rs = stat[rr][1];
    int nbase = (bx * 16 + rr) * 256;
    #pragma unroll
    for (int jj = 0; jj < 16; ++jj){
        int cc = i + 16 * jj;
        float z = (xs[rr * 264 + cc] - mu) * rs * g[cc] + beta[cc];
        out[nbase + cc] = 0.5f * z * (1.0f + erff(z * 0.70710678118654752f));
    }
}

extern "C" void kernel_launch(void* const* d_in, const int* in_sizes, int n_in,
                              void* d_out, int out_size, void* d_ws, size_t ws_size,
                              hipStream_t stream){
    const float* emb = (const float*)d_in[0];
    const int*   ei  = (const int*)d_in[1];
    const float* ipw = (const float*)d_in[2];
    const float* ipb = (const float*)d_in[3];
    const float* ow  = (const float*)d_in[4];
    const float* ob  = (const float*)d_in[5];
    const float* lw  = (const float*)d_in[6];
    const float* lb  = (const float*)d_in[7];
    const float* g   = (const float*)d_in[8];
    const float* bet = (const float*)d_in[9];

    char* ws = (char*)d_ws;
    unsigned*       adj  = (unsigned*)(ws);                    // 2 MiB
    int*            deg  = (int*)(ws + 2097152);               // 16 KiB
    unsigned short* bipw = (unsigned short*)(ws + 2113536);    // 384 KiB
    unsigned short* bow  = (unsigned short*)(ws + 2506752);    // 128 KiB
    unsigned short* blw  = (unsigned short*)(ws + 2637824);    // 128 KiB
    float*          qf   = (float*)(ws + 2768896);             // 4 MiB
    unsigned short* kb   = (unsigned short*)(ws + 6963200);    // 2 MiB
    unsigned short* vb   = (unsigned short*)(ws + 9060352);    // 2 MiB
    unsigned short* cpk  = (unsigned short*)(ws + 11157504);   // 2 MiB

    k_packw<<<160, 256, 0, stream>>>(ipw, ow, lw, bipw, bow, blw, adj);
    k_edges<<<EE / 256, 256, 0, stream>>>(ei, adj);
    k_gqkv <<<dim3(256, 3), 256, 0, stream>>>(emb, bipw, ipb, qf, kb, vb);
    k_attn <<<NN, 256, 0, stream>>>(qf, kb, vb, adj, deg, cpk);
    k_tail <<<256, 256, 0, stream>>>(cpk, bow, ob, emb, deg, blw, lb, g, bet, (float*)d_out);
}